// Round 5
// baseline (663.749 us; speedup 1.0000x reference)
//
#include <hip/hip_runtime.h>

// DiffSelfAttention on MI355X (gfx950).
// GEMMs: 2-term ((Ah+Al)*Bh) bf16 MFMA, single-barrier double-buffered staging (T3-min).
// Attention: plain-bf16 Q/K/V/P, KB=64, dbuf K/V staging, joint-max online softmax in
// log2 domain (scale*log2e baked into Q), row-sums via ones-MFMA, defer-max THR=8.

typedef unsigned short u16;
typedef __attribute__((ext_vector_type(8))) short bf16x8;
typedef __attribute__((ext_vector_type(4))) float f32x4;

#define MFMA16(a, b, c) __builtin_amdgcn_mfma_f32_16x16x32_bf16((a), (b), (c), 0, 0, 0)

#define LAMBDA_INIT_F 0.35550906759096926f
#define ONE_MINUS_LI_F 0.64449093240903074f
#define QSCALE 0.18033688011112042f   // 0.125 * log2(e): scores land in log2 domain
#define DEFER_THR 11.541560327111707f // 8 * log2(e)

__device__ __forceinline__ u16 f2bf(float f) {  // RNE (epilogues)
  union { float f; unsigned u; } v; v.f = f;
  unsigned r = v.u + 0x7fffu + ((v.u >> 16) & 1u);
  return (u16)(r >> 16);
}
__device__ __forceinline__ u16 fastbf(float f) {  // round-up-ties (P values, >=0)
  union { float f; unsigned u; } v; v.f = f;
  return (u16)((v.u + 0x8000u) >> 16);
}
__device__ __forceinline__ float bf2f(u16 h) {
  union { unsigned u; float f; } v; v.u = ((unsigned)h) << 16;
  return v.f;
}
__device__ __forceinline__ int sw3(int row) { return (row & 3) << 3; }
__device__ __forceinline__ int sw7(int row) { return (row & 7) << 3; }
__device__ __forceinline__ float fexp2(float x) { return __builtin_exp2f(x); }

__device__ __forceinline__ void gload16(const u16* g, u16* l) {
  __builtin_amdgcn_global_load_lds((const __attribute__((address_space(1))) void*)g,
                                   (__attribute__((address_space(3))) void*)l,
                                   16, 0, 0);
}

// ---------------- preprocessing ----------------

__global__ void lam_kernel(const float* __restrict__ q1, const float* __restrict__ k1,
                           const float* __restrict__ q2, const float* __restrict__ k2,
                           float* __restrict__ out) {
  int l = threadIdx.x;  // 64
  float p1 = q1[l] * k1[l];
  float p2 = q2[l] * k2[l];
#pragma unroll
  for (int m = 32; m >= 1; m >>= 1) {
    p1 += __shfl_xor(p1, m, 64);
    p2 += __shfl_xor(p2, m, 64);
  }
  if (l == 0) out[0] = expf(p1) - expf(p2) + LAMBDA_INIT_F;
}

// x [2048][2048] f32 -> hi/lo bf16, column-swizzled by sw3(row)
__global__ void split_x_kernel(const float* __restrict__ X, u16* __restrict__ H,
                               u16* __restrict__ L) {
  int idx = blockIdx.x * 256 + threadIdx.x;
  int t = idx >> 9;
  int c0 = (idx & 511) << 2;
  float4 v = *reinterpret_cast<const float4*>(X + ((size_t)t << 11) + c0);
  float vv[4] = {v.x, v.y, v.z, v.w};
  int s = sw3(t);
  size_t base = (size_t)t << 11;
#pragma unroll
  for (int j = 0; j < 4; ++j) {
    int c = (c0 + j) ^ s;
    u16 h = f2bf(vv[j]);
    H[base + c] = h;
    L[base + c] = f2bf(vv[j] - bf2f(h));
  }
}

// W [K][N] f32 -> W^T [N][K] bf16 (hi only), column(k)-swizzled by sw3(n)
__global__ void transpose_kernel(const float* __restrict__ W, u16* __restrict__ TH, int K,
                                 int N) {
  __shared__ float tile[64][65];
  int bk = blockIdx.x * 64, bn = blockIdx.y * 64;
  for (int i = threadIdx.x; i < 64 * 64; i += 256) {
    int r = i >> 6, c = i & 63;
    tile[r][c] = W[(size_t)(bk + r) * N + bn + c];
  }
  __syncthreads();
  for (int i = threadIdx.x; i < 64 * 64; i += 256) {
    int r = i >> 6, c = i & 63;
    float v = tile[c][r];
    int n = bn + r, k = bk + c;
    TH[(size_t)n * K + (k ^ sw3(n))] = f2bf(v);
  }
}

// ---------------- bf16x2 GEMM: C = (Ah+Al) @ Bh^T, dbuf single-barrier ----------------
// EPI 0: -> qk_h (q scaled by QSCALE, k sw7) + vt_h (V^T, sw7 on t).  EPI 1: fp32 -> outp
template <int EPI, int BM>
__global__ __launch_bounds__(256, 3) void gemm_bf16x2(
    const u16* __restrict__ Agh, const u16* __restrict__ Agl, const u16* __restrict__ Bgh,
    int N, int K, u16* __restrict__ qk_h, u16* __restrict__ vt_h, float* __restrict__ outp) {
  constexpr int AC = BM / 16;     // 1KB chunks per A array
  constexpr int CPW = (2 * AC + 8) / 4;
  constexpr int ASZ = BM * 32;    // elems per A array
  constexpr int MR = BM / 32;     // m-fragments per wave
  __shared__ __align__(16) u16 LB[2][(2 * BM + 128) * 32];
  const int tid = threadIdx.x;
  const int w = tid >> 6, lane = tid & 63;
  const int lr = lane & 15, kg = lane >> 4;
  const int bn0 = blockIdx.x * 128, bm0 = blockIdx.y * BM;
  const int wm = (w >> 1) * (BM / 2), wn = (w & 1) * 64;
  const int srow = lane >> 2, scol = (lane & 3) << 3;

  auto STAGE = [&](int k0, int buf) {
#pragma unroll
    for (int j = 0; j < CPW; ++j) {
      int i = w * CPW + j;
      int a = (i < AC) ? 0 : (i < 2 * AC) ? 1 : 2;
      int c = i - ((a == 0) ? 0 : (a == 1) ? AC : 2 * AC);
      const u16* src = (a == 0) ? Agh : (a == 1) ? Agl : Bgh;
      int tb = (a < 2) ? bm0 : bn0;
      gload16(src + (size_t)(tb + c * 16 + srow) * K + k0 + scol,
              &LB[buf][a * ASZ + c * 512]);
    }
  };

  f32x4 acc[MR][4];
  const f32x4 VZ = {0.f, 0.f, 0.f, 0.f};
#pragma unroll
  for (int m = 0; m < MR; ++m)
#pragma unroll
    for (int n = 0; n < 4; ++n) acc[m][n] = VZ;

  STAGE(0, 0);
  __syncthreads();  // drains vmcnt(0): buf0 ready
  int cur = 0;
  for (int k0 = 0; k0 < K; k0 += 32) {
    if (k0 + 32 < K) STAGE(k0 + 32, cur ^ 1);  // in flight during compute

    const u16* LAh = &LB[cur][0];
    const u16* LAl = &LB[cur][ASZ];
    const u16* LBh = &LB[cur][2 * ASZ];
    bf16x8 ah[MR], al[MR], bh[4];
#pragma unroll
    for (int m = 0; m < MR; ++m) {
      int row = wm + m * 16 + lr;
      int off = (row << 5) + ((kg << 3) ^ sw3(row));
      ah[m] = *reinterpret_cast<const bf16x8*>(LAh + off);
      al[m] = *reinterpret_cast<const bf16x8*>(LAl + off);
    }
#pragma unroll
    for (int n = 0; n < 4; ++n) {
      int row = wn + n * 16 + lr;
      int off = (row << 5) + ((kg << 3) ^ sw3(row));
      bh[n] = *reinterpret_cast<const bf16x8*>(LBh + off);
    }
#pragma unroll
    for (int m = 0; m < MR; ++m)
#pragma unroll
      for (int n = 0; n < 4; ++n) {
        acc[m][n] = MFMA16(ah[m], bh[n], acc[m][n]);
        acc[m][n] = MFMA16(al[m], bh[n], acc[m][n]);
      }

    __syncthreads();  // drains staged loads + all reads of cur
    cur ^= 1;
  }

#pragma unroll
  for (int m = 0; m < MR; ++m) {
#pragma unroll
    for (int n = 0; n < 4; ++n) {
#pragma unroll
      for (int r = 0; r < 4; ++r) {
        int row = bm0 + wm + m * 16 + (kg << 2) + r;  // C/D: row=(lane>>4)*4+reg
        int col = bn0 + wn + n * 16 + lr;             //      col=lane&15
        float v = acc[m][n][r];
        if (EPI == 0) {
          if (col < 2048) v *= QSCALE;  // bake softmax scale * log2e into Q
          u16 hh = f2bf(v);
          if (col < 4096) {
            int cc = (col < 2048) ? col : (2048 + ((col - 2048) ^ sw7(row)));
            qk_h[((size_t)row << 12) + cc] = hh;
          } else {
            int vc = col - 4096;
            vt_h[((size_t)vc << 11) + (row ^ sw7(vc))] = hh;
          }
        } else {
          outp[(size_t)row * N + col] = v;
        }
      }
    }
  }
}

// ---------------- fused dual flash-attention + lambda-combine + RMS norm ----------------
// grid (T/64, 16 heads), 4 waves; wave owns 16 q-rows; KB=64; dbuf staging, 1 barrier/tile.
__global__ __launch_bounds__(256, 2) void diff_attn_kernel(
    const u16* __restrict__ qk_h, const u16* __restrict__ vt_h, const float* __restrict__ lam_p,
    const float* __restrict__ rms_scale, u16* __restrict__ at_h, u16* __restrict__ at_l) {
  __shared__ __align__(16) u16 KL[2][2][64][64];   // [buf][stream] 32 KB, sw7 d-chunks
  __shared__ __align__(16) u16 VL[2][128][64];     // [buf] V^T 32 KB, sw7 t-chunks
  __shared__ __align__(16) u16 PL[4][2][16][64];   // per-wave P 16 KB, rotation-swizzled

  const int tid = threadIdx.x;
  const int w = tid >> 6, lane = tid & 63;
  const int lr = lane & 15, kg = lane >> 4;
  const int h = blockIdx.y;
  const int qb = blockIdx.x * 64 + w * 16;
  const float lam = lam_p[0];
  const f32x4 VZ = {0.f, 0.f, 0.f, 0.f};
  const bf16x8 ONES = {0x3f80, 0x3f80, 0x3f80, 0x3f80, 0x3f80, 0x3f80, 0x3f80, 0x3f80};

  // Q fragments (pre-scaled by QSCALE in GEMM1 epilogue): [stream][kchunk]
  bf16x8 qf[2][2];
  {
    const size_t qrb = ((size_t)(qb + lr)) << 12;
#pragma unroll
    for (int s = 0; s < 2; ++s) {
      int qo = h * 64 + s * 1024;
#pragma unroll
      for (int kc = 0; kc < 2; ++kc)
        qf[s][kc] = *reinterpret_cast<const bf16x8*>(qk_h + qrb + qo + kc * 32 + (kg << 3));
    }
  }

  f32x4 o1[8], o2[8];
#pragma unroll
  for (int n = 0; n < 8; ++n) { o1[n] = VZ; o2[n] = VZ; }
  float m[4], l1[4], l2[4];
#pragma unroll
  for (int r = 0; r < 4; ++r) { m[r] = -1e30f; l1[r] = l2[r] = 0.f; }

  const int srow8 = lane >> 3, scol8 = (lane & 7) << 3;
  const int koff = 2048 + h * 64 + w * 1024;  // valid for w<2

  auto STAGE = [&](int kt, int buf) {
    if (w < 2) {  // wave0->K1, wave1->K2
#pragma unroll
      for (int c = 0; c < 8; ++c)
        gload16(qk_h + (((size_t)(kt + c * 8 + srow8)) << 12) + koff + scol8,
                &KL[buf][w][c * 8][0]);
    } else {  // waves 2,3 -> V halves
      const int vb = (w - 2) * 64;
#pragma unroll
      for (int c = 0; c < 8; ++c)
        gload16(vt_h + (((size_t)(h * 128 + vb + c * 8 + srow8)) << 11) + kt + scol8,
                &VL[buf][vb + c * 8][0]);
    }
  };

  STAGE(0, 0);
  __syncthreads();
  int cur = 0;
  for (int kt = 0; kt < 2048; kt += 64) {
    if (kt + 64 < 2048) STAGE(kt + 64, cur ^ 1);

    // S = Q K^T (scores in log2 domain; both streams)
    f32x4 s1[4], s2[4];
#pragma unroll
    for (int n = 0; n < 4; ++n) { s1[n] = VZ; s2[n] = VZ; }
#pragma unroll
    for (int n = 0; n < 4; ++n) {
      int key = n * 16 + lr;
#pragma unroll
      for (int kc = 0; kc < 2; ++kc) {
        int off = (key << 6) + (((kc << 5) + (kg << 3)) ^ sw7(key));
        bf16x8 k1 = *reinterpret_cast<const bf16x8*>(&KL[cur][0][0][0] + off);
        bf16x8 k2 = *reinterpret_cast<const bf16x8*>(&KL[cur][1][0][0] + off);
        s1[n] = MFMA16(qf[0][kc], k1, s1[n]);
        s2[n] = MFMA16(qf[1][kc], k2, s2[n]);
      }
    }

    // joint-max online softmax, defer-max
    float tmax[4];
#pragma unroll
    for (int r = 0; r < 4; ++r) {
      float t = fmaxf(fmaxf(fmaxf(s1[0][r], s1[1][r]), fmaxf(s1[2][r], s1[3][r])),
                      fmaxf(fmaxf(s2[0][r], s2[1][r]), fmaxf(s2[2][r], s2[3][r])));
      t = fmaxf(t, __shfl_xor(t, 1, 64));
      t = fmaxf(t, __shfl_xor(t, 2, 64));
      t = fmaxf(t, __shfl_xor(t, 4, 64));
      t = fmaxf(t, __shfl_xor(t, 8, 64));
      tmax[r] = t;
    }
    int need = 0;
#pragma unroll
    for (int r = 0; r < 4; ++r) need |= (tmax[r] > m[r] + DEFER_THR) ? 1 : 0;
    if (__any(need)) {
#pragma unroll
      for (int r = 0; r < 4; ++r) {
        float mn = fmaxf(m[r], tmax[r]);
        float corr = fexp2(m[r] - mn);
        m[r] = mn;
        l1[r] *= corr;
        l2[r] *= corr;
#pragma unroll
        for (int n = 0; n < 8; ++n) { o1[n][r] *= corr; o2[n][r] *= corr; }
      }
    }
    // P = exp2(s - m), store rotation-swizzled
#pragma unroll
    for (int n = 0; n < 4; ++n)
#pragma unroll
      for (int r = 0; r < 4; ++r) {
        float p1 = fexp2(s1[n][r] - m[r]);
        float p2 = fexp2(s2[n][r] - m[r]);
        int qp = (n * 2 + (lr >> 3) + kg + 2 * r) & 7;
        int idx = qp * 8 + (lr & 7);
        PL[w][0][4 * kg + r][idx] = fastbf(p1);
        PL[w][1][4 * kg + r][idx] = fastbf(p2);
      }

    // read back P as A-fragments; row-sums via ones-MFMA
    bf16x8 pa1[2], pa2[2];
#pragma unroll
    for (int ks = 0; ks < 2; ++ks) {
      int qp = (ks * 4 + kg + (lr >> 2) + 2 * (lr & 3)) & 7;
      pa1[ks] = *reinterpret_cast<const bf16x8*>(&PL[w][0][lr][qp * 8]);
      pa2[ks] = *reinterpret_cast<const bf16x8*>(&PL[w][1][lr][qp * 8]);
    }
    f32x4 lacc1 = MFMA16(pa1[1], ONES, MFMA16(pa1[0], ONES, VZ));
    f32x4 lacc2 = MFMA16(pa2[1], ONES, MFMA16(pa2[0], ONES, VZ));
#pragma unroll
    for (int r = 0; r < 4; ++r) { l1[r] += lacc1[r]; l2[r] += lacc2[r]; }

    // O += P V; V fragments shared across streams
#pragma unroll
    for (int n = 0; n < 8; ++n) {
      int vd = n * 16 + lr;
#pragma unroll
      for (int ks = 0; ks < 2; ++ks) {
        int off = (vd << 6) + (((ks << 5) + (kg << 3)) ^ sw7(vd));
        bf16x8 vf = *reinterpret_cast<const bf16x8*>(&VL[cur][0][0] + off);
        o1[n] = MFMA16(pa1[ks], vf, o1[n]);
        o2[n] = MFMA16(pa2[ks], vf, o2[n]);
      }
    }

    __syncthreads();  // drains staged loads (vmcnt) + LDS reads of cur
    cur ^= 1;
  }

  // epilogue: a1 - lam*a2, RMS over 128, * rms_scale * (1-LAMBDA_INIT); hi/lo split for GEMM2
  float nsc[4];
  {
    float il1[4], il2[4], ss[4];
#pragma unroll
    for (int r = 0; r < 4; ++r) { il1[r] = 1.f / l1[r]; il2[r] = 1.f / l2[r]; ss[r] = 0.f; }
#pragma unroll
    for (int n = 0; n < 8; ++n)
#pragma unroll
      for (int r = 0; r < 4; ++r) {
        float v = o1[n][r] * il1[r] - lam * (o2[n][r] * il2[r]);
        o1[n][r] = v;
        ss[r] += v * v;
      }
#pragma unroll
    for (int r = 0; r < 4; ++r) {
      float t = ss[r];
      t += __shfl_xor(t, 1, 64);
      t += __shfl_xor(t, 2, 64);
      t += __shfl_xor(t, 4, 64);
      t += __shfl_xor(t, 8, 64);
      nsc[r] = rsqrtf(t * (1.f / 128.f) + 1e-6f) * ONE_MINUS_LI_F;
    }
  }
#pragma unroll
  for (int n = 0; n < 8; ++n) {
    float rs = rms_scale[n * 16 + lr];
#pragma unroll
    for (int r = 0; r < 4; ++r) {
      int row = qb + (kg << 2) + r;
      int col = h * 128 + n * 16 + lr;
      float v = o1[n][r] * nsc[r] * rs;
      u16 hh = f2bf(v);
      int cc = col ^ sw3(row);
      at_h[((size_t)row << 11) + cc] = hh;
      at_l[((size_t)row << 11) + cc] = f2bf(v - bf2f(hh));
    }
  }
}

// ---------------- launch ----------------

extern "C" void kernel_launch(void* const* d_in, const int* in_sizes, int n_in, void* d_out,
                              int out_size, void* d_ws, size_t ws_size, hipStream_t stream) {
  (void)in_sizes; (void)n_in; (void)out_size;
  const float* x = (const float*)d_in[0];
  const float* wqkv = (const float*)d_in[1];
  const float* wprj = (const float*)d_in[2];
  const float* lq1 = (const float*)d_in[3];
  const float* lk1 = (const float*)d_in[4];
  const float* lq2 = (const float*)d_in[5];
  const float* lk2 = (const float*)d_in[6];
  const float* rms = (const float*)d_in[7];
  float* out = (float*)d_out;

  char* p = (char*)d_ws;
  auto take = [&](size_t n) { char* r = p; p += (n + 255) & ~(size_t)255; return r; };
  float* lam = (float*)take(256);
  u16* x_h = (u16*)take(2048ull * 2048 * 2);
  u16* x_l = (u16*)take(2048ull * 2048 * 2);
  u16* wqT_h = (u16*)take(6144ull * 2048 * 2);
  u16* wpT_h = (u16*)take(2048ull * 2048 * 2);
  u16* qk_h = (u16*)take(2048ull * 4096 * 2);
  u16* vt_h = (u16*)take(2048ull * 2048 * 2);
  u16* at_h = (u16*)take(2048ull * 2048 * 2);
  u16* at_l = (u16*)take(2048ull * 2048 * 2);
  if ((size_t)(p - (char*)d_ws) > ws_size) return;

  lam_kernel<<<1, 64, 0, stream>>>(lq1, lk1, lq2, lk2, lam);
  split_x_kernel<<<4096, 256, 0, stream>>>(x, x_h, x_l);
  transpose_kernel<<<dim3(32, 96), 256, 0, stream>>>(wqkv, wqT_h, 2048, 6144);
  transpose_kernel<<<dim3(32, 32), 256, 0, stream>>>(wprj, wpT_h, 2048, 2048);

  // qkv = x @ w_qkv (M=2048, N=6144, K=2048) -> qk_h (q pre-scaled) + vt_h
  gemm_bf16x2<0, 128><<<dim3(48, 16), 256, 0, stream>>>(x_h, x_l, wqT_h, 6144, 2048, qk_h,
                                                        vt_h, nullptr);
  // dual flash attention + combine + RMS
  diff_attn_kernel<<<dim3(32, 16), 256, 0, stream>>>(qk_h, vt_h, lam, rms, at_h, at_l);
  // out = attn @ w_proj (M=N=K=2048), BM=64 -> 512 blocks (2/CU)
  gemm_bf16x2<1, 64><<<dim3(16, 32), 256, 0, stream>>>(at_h, at_l, wpT_h, 2048, 2048, nullptr,
                                                       nullptr, out);
}

// Round 7
// 391.508 us; speedup vs baseline: 1.6954x; 1.6954x over previous
//
#include <hip/hip_runtime.h>

// DiffSelfAttention on MI355X (gfx950).
// ROUND 7 (= round-6 resubmit; rounds 3,4,6 were broker timeouts, never measured).
// Revert to round-2's measured-good 2-barrier single-buffer loops (the round-5
// issue-early/dbuf hybrid regressed GEMM1 2.2x at constant occupancy — do not reintroduce).
// Kept from round 5 (HW-verified math, structure-orthogonal): QSCALE*log2e baked into Q,
// joint-max log2-domain softmax + defer-max, ones-MFMA row-sums, fastbf P, GEMM2 BM=64.

typedef unsigned short u16;
typedef __attribute__((ext_vector_type(8))) short bf16x8;
typedef __attribute__((ext_vector_type(4))) float f32x4;

#define MFMA16(a, b, c) __builtin_amdgcn_mfma_f32_16x16x32_bf16((a), (b), (c), 0, 0, 0)

#define LAMBDA_INIT_F 0.35550906759096926f
#define ONE_MINUS_LI_F 0.64449093240903074f
#define QSCALE 0.18033688011112042f   // 0.125 * log2(e): scores land in log2 domain
#define DEFER_THR 11.541560327111707f // 8 * log2(e)

__device__ __forceinline__ u16 f2bf(float f) {  // RNE (epilogues)
  union { float f; unsigned u; } v; v.f = f;
  unsigned r = v.u + 0x7fffu + ((v.u >> 16) & 1u);
  return (u16)(r >> 16);
}
__device__ __forceinline__ u16 fastbf(float f) {  // round-up-ties (P values, >=0)
  union { float f; unsigned u; } v; v.f = f;
  return (u16)((v.u + 0x8000u) >> 16);
}
__device__ __forceinline__ float bf2f(u16 h) {
  union { unsigned u; float f; } v; v.u = ((unsigned)h) << 16;
  return v.f;
}
__device__ __forceinline__ int sw3(int row) { return (row & 3) << 3; }
__device__ __forceinline__ int sw7(int row) { return (row & 7) << 3; }
__device__ __forceinline__ float fexp2(float x) { return __builtin_exp2f(x); }

__device__ __forceinline__ void gload16(const u16* g, u16* l) {
  __builtin_amdgcn_global_load_lds((const __attribute__((address_space(1))) void*)g,
                                   (__attribute__((address_space(3))) void*)l,
                                   16, 0, 0);
}

// ---------------- preprocessing ----------------

__global__ void lam_kernel(const float* __restrict__ q1, const float* __restrict__ k1,
                           const float* __restrict__ q2, const float* __restrict__ k2,
                           float* __restrict__ out) {
  int l = threadIdx.x;  // 64
  float p1 = q1[l] * k1[l];
  float p2 = q2[l] * k2[l];
#pragma unroll
  for (int m = 32; m >= 1; m >>= 1) {
    p1 += __shfl_xor(p1, m, 64);
    p2 += __shfl_xor(p2, m, 64);
  }
  if (l == 0) out[0] = expf(p1) - expf(p2) + LAMBDA_INIT_F;
}

// x [2048][2048] f32 -> hi/lo bf16, column-swizzled by sw3(row)
__global__ void split_x_kernel(const float* __restrict__ X, u16* __restrict__ H,
                               u16* __restrict__ L) {
  int idx = blockIdx.x * 256 + threadIdx.x;
  int t = idx >> 9;
  int c0 = (idx & 511) << 2;
  float4 v = *reinterpret_cast<const float4*>(X + ((size_t)t << 11) + c0);
  float vv[4] = {v.x, v.y, v.z, v.w};
  int s = sw3(t);
  size_t base = (size_t)t << 11;
#pragma unroll
  for (int j = 0; j < 4; ++j) {
    int c = (c0 + j) ^ s;
    u16 h = f2bf(vv[j]);
    H[base + c] = h;
    L[base + c] = f2bf(vv[j] - bf2f(h));
  }
}

// W [K][N] f32 -> W^T [N][K] bf16 (hi only), column(k)-swizzled by sw3(n)
__global__ void transpose_kernel(const float* __restrict__ W, u16* __restrict__ TH, int K,
                                 int N) {
  __shared__ float tile[64][65];
  int bk = blockIdx.x * 64, bn = blockIdx.y * 64;
  for (int i = threadIdx.x; i < 64 * 64; i += 256) {
    int r = i >> 6, c = i & 63;
    tile[r][c] = W[(size_t)(bk + r) * N + bn + c];
  }
  __syncthreads();
  for (int i = threadIdx.x; i < 64 * 64; i += 256) {
    int r = i >> 6, c = i & 63;
    float v = tile[c][r];
    int n = bn + r, k = bk + c;
    TH[(size_t)n * K + (k ^ sw3(n))] = f2bf(v);
  }
}

// ---------------- bf16x2 GEMM: C = (Ah+Al) @ Bh^T, 2-barrier single-buffer ----------------
// EPI 0: -> qk_h (q scaled by QSCALE, k sw7) + vt_h (V^T, sw7 on t).  EPI 1: fp32 -> outp
template <int EPI, int BM>
__global__ __launch_bounds__(256, 3) void gemm_bf16x2(
    const u16* __restrict__ Agh, const u16* __restrict__ Agl, const u16* __restrict__ Bgh,
    int N, int K, u16* __restrict__ qk_h, u16* __restrict__ vt_h, float* __restrict__ outp) {
  constexpr int AC = BM / 16;       // 1KB chunks per A array
  constexpr int CPW = (2 * AC + 8) / 4;  // chunks per wave
  constexpr int ASZ = BM * 32;      // elems per A array
  constexpr int MR = BM / 32;       // m-fragments per wave
  __shared__ __align__(16) u16 LA[(2 * BM + 128) * 32];  // Ah, Al, Bh
  const int tid = threadIdx.x;
  const int w = tid >> 6, lane = tid & 63;
  const int lr = lane & 15, kg = lane >> 4;
  const int bn0 = blockIdx.x * 128, bm0 = blockIdx.y * BM;
  const int wm = (w >> 1) * (BM / 2), wn = (w & 1) * 64;
  const int srow = lane >> 2, scol = (lane & 3) << 3;

  f32x4 acc[MR][4];
  const f32x4 VZ = {0.f, 0.f, 0.f, 0.f};
#pragma unroll
  for (int m = 0; m < MR; ++m)
#pragma unroll
    for (int n = 0; n < 4; ++n) acc[m][n] = VZ;

  for (int k0 = 0; k0 < K; k0 += 32) {
    __syncthreads();  // previous tile's reads complete
#pragma unroll
    for (int j = 0; j < CPW; ++j) {
      int i = w * CPW + j;
      int a = (i < AC) ? 0 : (i < 2 * AC) ? 1 : 2;
      int c = i - ((a == 0) ? 0 : (a == 1) ? AC : 2 * AC);
      const u16* src = (a == 0) ? Agh : (a == 1) ? Agl : Bgh;
      int tb = (a < 2) ? bm0 : bn0;
      gload16(src + (size_t)(tb + c * 16 + srow) * K + k0 + scol, &LA[a * ASZ + c * 512]);
    }
    __syncthreads();  // staging drained (vmcnt(0) before barrier)

    bf16x8 ah[MR], al[MR], bh[4];
#pragma unroll
    for (int m = 0; m < MR; ++m) {
      int row = wm + m * 16 + lr;
      int off = (row << 5) + ((kg << 3) ^ sw3(row));
      ah[m] = *reinterpret_cast<const bf16x8*>(&LA[0] + off);
      al[m] = *reinterpret_cast<const bf16x8*>(&LA[ASZ] + off);
    }
#pragma unroll
    for (int n = 0; n < 4; ++n) {
      int row = wn + n * 16 + lr;
      int off = (row << 5) + ((kg << 3) ^ sw3(row));
      bh[n] = *reinterpret_cast<const bf16x8*>(&LA[2 * ASZ] + off);
    }
#pragma unroll
    for (int m = 0; m < MR; ++m)
#pragma unroll
      for (int n = 0; n < 4; ++n) {
        acc[m][n] = MFMA16(ah[m], bh[n], acc[m][n]);
        acc[m][n] = MFMA16(al[m], bh[n], acc[m][n]);
      }
  }

#pragma unroll
  for (int m = 0; m < MR; ++m) {
#pragma unroll
    for (int n = 0; n < 4; ++n) {
#pragma unroll
      for (int r = 0; r < 4; ++r) {
        int row = bm0 + wm + m * 16 + (kg << 2) + r;  // C/D: row=(lane>>4)*4+reg
        int col = bn0 + wn + n * 16 + lr;             //      col=lane&15
        float v = acc[m][n][r];
        if (EPI == 0) {
          if (col < 2048) v *= QSCALE;  // bake softmax scale * log2e into Q
          u16 hh = f2bf(v);
          if (col < 4096) {  // q plain; k sw7-swizzled within 64-col head slice
            int cc = (col < 2048) ? col : (2048 + ((col - 2048) ^ sw7(row)));
            qk_h[((size_t)row << 12) + cc] = hh;
          } else {  // v -> transposed [vc][t], t sw7-swizzled by vc
            int vc = col - 4096;
            vt_h[((size_t)vc << 11) + (row ^ sw7(vc))] = hh;
          }
        } else {
          outp[(size_t)row * N + col] = v;
        }
      }
    }
  }
}

// ---------------- fused dual flash-attention + lambda-combine + RMS norm ----------------
// grid (T/64, 16 heads), 4 waves; wave owns 16 q-rows; KB=64; 2-barrier single-buffer.
__global__ __launch_bounds__(256, 2) void diff_attn_kernel(
    const u16* __restrict__ qk_h, const u16* __restrict__ vt_h, const float* __restrict__ lam_p,
    const float* __restrict__ rms_scale, u16* __restrict__ at_h, u16* __restrict__ at_l) {
  __shared__ __align__(16) u16 KL[2][64][64];     // K1, K2 (16 KB), sw7 on d-chunks
  __shared__ __align__(16) u16 VL[128][64];       // V^T (16 KB), sw7 on t-chunks
  __shared__ __align__(16) u16 PL[4][2][16][64];  // per-wave P (16 KB), rotation-swizzled

  const int tid = threadIdx.x;
  const int w = tid >> 6, lane = tid & 63;
  const int lr = lane & 15, kg = lane >> 4;
  const int h = blockIdx.y;
  const int qb = blockIdx.x * 64 + w * 16;
  const float lam = lam_p[0];
  const f32x4 VZ = {0.f, 0.f, 0.f, 0.f};
  const bf16x8 ONES = {0x3f80, 0x3f80, 0x3f80, 0x3f80, 0x3f80, 0x3f80, 0x3f80, 0x3f80};

  // Q fragments (pre-scaled by QSCALE in GEMM1 epilogue): [stream][kchunk]
  bf16x8 qf[2][2];
  {
    const size_t qrb = ((size_t)(qb + lr)) << 12;
#pragma unroll
    for (int s = 0; s < 2; ++s) {
      int qo = h * 64 + s * 1024;
#pragma unroll
      for (int kc = 0; kc < 2; ++kc)
        qf[s][kc] = *reinterpret_cast<const bf16x8*>(qk_h + qrb + qo + kc * 32 + (kg << 3));
    }
  }

  f32x4 o1[8], o2[8];
#pragma unroll
  for (int n = 0; n < 8; ++n) { o1[n] = VZ; o2[n] = VZ; }
  float m[4], l1[4], l2[4];
#pragma unroll
  for (int r = 0; r < 4; ++r) { m[r] = -1e30f; l1[r] = l2[r] = 0.f; }

  const int srow8 = lane >> 3, scol8 = (lane & 7) << 3;
  const int koff = 2048 + h * 64 + w * 1024;  // valid for w<2

  for (int kt = 0; kt < 2048; kt += 64) {
    __syncthreads();  // previous tile's LDS reads complete
    if (w < 2) {      // wave0->K1, wave1->K2
#pragma unroll
      for (int c = 0; c < 8; ++c)
        gload16(qk_h + (((size_t)(kt + c * 8 + srow8)) << 12) + koff + scol8, &KL[w][c * 8][0]);
    } else {          // waves 2,3 -> V halves
      const int vb = (w - 2) * 64;
#pragma unroll
      for (int c = 0; c < 8; ++c)
        gload16(vt_h + (((size_t)(h * 128 + vb + c * 8 + srow8)) << 11) + kt + scol8,
                &VL[vb + c * 8][0]);
    }
    __syncthreads();  // staging drained

    // S = Q K^T (scores in log2 domain; both streams)
    f32x4 s1[4], s2[4];
#pragma unroll
    for (int n = 0; n < 4; ++n) { s1[n] = VZ; s2[n] = VZ; }
#pragma unroll
    for (int n = 0; n < 4; ++n) {
      int key = n * 16 + lr;
#pragma unroll
      for (int kc = 0; kc < 2; ++kc) {
        int off = (key << 6) + (((kc << 5) + (kg << 3)) ^ sw7(key));
        bf16x8 k1 = *reinterpret_cast<const bf16x8*>(&KL[0][0][0] + off);
        bf16x8 k2 = *reinterpret_cast<const bf16x8*>(&KL[1][0][0] + off);
        s1[n] = MFMA16(qf[0][kc], k1, s1[n]);
        s2[n] = MFMA16(qf[1][kc], k2, s2[n]);
      }
    }

    // joint-max online softmax, defer-max
    float tmax[4];
#pragma unroll
    for (int r = 0; r < 4; ++r) {
      float t = fmaxf(fmaxf(fmaxf(s1[0][r], s1[1][r]), fmaxf(s1[2][r], s1[3][r])),
                      fmaxf(fmaxf(s2[0][r], s2[1][r]), fmaxf(s2[2][r], s2[3][r])));
      t = fmaxf(t, __shfl_xor(t, 1, 64));
      t = fmaxf(t, __shfl_xor(t, 2, 64));
      t = fmaxf(t, __shfl_xor(t, 4, 64));
      t = fmaxf(t, __shfl_xor(t, 8, 64));
      tmax[r] = t;
    }
    int need = 0;
#pragma unroll
    for (int r = 0; r < 4; ++r) need |= (tmax[r] > m[r] + DEFER_THR) ? 1 : 0;
    if (__any(need)) {
#pragma unroll
      for (int r = 0; r < 4; ++r) {
        float mn = fmaxf(m[r], tmax[r]);
        float corr = fexp2(m[r] - mn);
        m[r] = mn;
        l1[r] *= corr;
        l2[r] *= corr;
#pragma unroll
        for (int n = 0; n < 8; ++n) { o1[n][r] *= corr; o2[n][r] *= corr; }
      }
    }
    // P = exp2(s - m), store rotation-swizzled
#pragma unroll
    for (int n = 0; n < 4; ++n)
#pragma unroll
      for (int r = 0; r < 4; ++r) {
        float p1 = fexp2(s1[n][r] - m[r]);
        float p2 = fexp2(s2[n][r] - m[r]);
        int qp = (n * 2 + (lr >> 3) + kg + 2 * r) & 7;
        int idx = qp * 8 + (lr & 7);
        PL[w][0][4 * kg + r][idx] = fastbf(p1);
        PL[w][1][4 * kg + r][idx] = fastbf(p2);
      }

    // read back P as A-fragments; row-sums via ones-MFMA
    bf16x8 pa1[2], pa2[2];
#pragma unroll
    for (int ks = 0; ks < 2; ++ks) {
      int qp = (ks * 4 + kg + (lr >> 2) + 2 * (lr & 3)) & 7;
      pa1[ks] = *reinterpret_cast<const bf16x8*>(&PL[w][0][lr][qp * 8]);
      pa2[ks] = *reinterpret_cast<const bf16x8*>(&PL[w][1][lr][qp * 8]);
    }
    f32x4 lacc1 = MFMA16(pa1[1], ONES, MFMA16(pa1[0], ONES, VZ));
    f32x4 lacc2 = MFMA16(pa2[1], ONES, MFMA16(pa2[0], ONES, VZ));
#pragma unroll
    for (int r = 0; r < 4; ++r) { l1[r] += lacc1[r]; l2[r] += lacc2[r]; }

    // O += P V; V fragments shared across streams
#pragma unroll
    for (int n = 0; n < 8; ++n) {
      int vd = n * 16 + lr;
#pragma unroll
      for (int ks = 0; ks < 2; ++ks) {
        int off = (vd << 6) + (((ks << 5) + (kg << 3)) ^ sw7(vd));
        bf16x8 vf = *reinterpret_cast<const bf16x8*>(&VL[0][0] + off);
        o1[n] = MFMA16(pa1[ks], vf, o1[n]);
        o2[n] = MFMA16(pa2[ks], vf, o2[n]);
      }
    }
  }

  // epilogue: a1 - lam*a2, RMS over 128, * rms_scale * (1-LAMBDA_INIT); hi/lo split for GEMM2
  float nsc[4];
  {
    float il1[4], il2[4], ss[4];
#pragma unroll
    for (int r = 0; r < 4; ++r) { il1[r] = 1.f / l1[r]; il2[r] = 1.f / l2[r]; ss[r] = 0.f; }
#pragma unroll
    for (int n = 0; n < 8; ++n)
#pragma unroll
      for (int r = 0; r < 4; ++r) {
        float v = o1[n][r] * il1[r] - lam * (o2[n][r] * il2[r]);
        o1[n][r] = v;
        ss[r] += v * v;
      }
#pragma unroll
    for (int r = 0; r < 4; ++r) {
      float t = ss[r];
      t += __shfl_xor(t, 1, 64);
      t += __shfl_xor(t, 2, 64);
      t += __shfl_xor(t, 4, 64);
      t += __shfl_xor(t, 8, 64);
      nsc[r] = rsqrtf(t * (1.f / 128.f) + 1e-6f) * ONE_MINUS_LI_F;
    }
  }
#pragma unroll
  for (int n = 0; n < 8; ++n) {
    float rs = rms_scale[n * 16 + lr];
#pragma unroll
    for (int r = 0; r < 4; ++r) {
      int row = qb + (kg << 2) + r;
      int col = h * 128 + n * 16 + lr;
      float v = o1[n][r] * nsc[r] * rs;
      u16 hh = f2bf(v);
      int cc = col ^ sw3(row);
      at_h[((size_t)row << 11) + cc] = hh;
      at_l[((size_t)row << 11) + cc] = f2bf(v - bf2f(hh));
    }
  }
}

// ---------------- launch ----------------

extern "C" void kernel_launch(void* const* d_in, const int* in_sizes, int n_in, void* d_out,
                              int out_size, void* d_ws, size_t ws_size, hipStream_t stream) {
  (void)in_sizes; (void)n_in; (void)out_size;
  const float* x = (const float*)d_in[0];
  const float* wqkv = (const float*)d_in[1];
  const float* wprj = (const float*)d_in[2];
  const float* lq1 = (const float*)d_in[3];
  const float* lk1 = (const float*)d_in[4];
  const float* lq2 = (const float*)d_in[5];
  const float* lk2 = (const float*)d_in[6];
  const float* rms = (const float*)d_in[7];
  float* out = (float*)d_out;

  char* p = (char*)d_ws;
  auto take = [&](size_t n) { char* r = p; p += (n + 255) & ~(size_t)255; return r; };
  float* lam = (float*)take(256);
  u16* x_h = (u16*)take(2048ull * 2048 * 2);
  u16* x_l = (u16*)take(2048ull * 2048 * 2);
  u16* wqT_h = (u16*)take(6144ull * 2048 * 2);
  u16* wpT_h = (u16*)take(2048ull * 2048 * 2);
  u16* qk_h = (u16*)take(2048ull * 4096 * 2);
  u16* vt_h = (u16*)take(2048ull * 2048 * 2);
  u16* at_h = (u16*)take(2048ull * 2048 * 2);
  u16* at_l = (u16*)take(2048ull * 2048 * 2);
  if ((size_t)(p - (char*)d_ws) > ws_size) return;

  lam_kernel<<<1, 64, 0, stream>>>(lq1, lk1, lq2, lk2, lam);
  split_x_kernel<<<4096, 256, 0, stream>>>(x, x_h, x_l);
  transpose_kernel<<<dim3(32, 96), 256, 0, stream>>>(wqkv, wqT_h, 2048, 6144);
  transpose_kernel<<<dim3(32, 32), 256, 0, stream>>>(wprj, wpT_h, 2048, 2048);

  // qkv = x @ w_qkv (M=2048, N=6144, K=2048) -> qk_h (q pre-scaled) + vt_h
  gemm_bf16x2<0, 128><<<dim3(48, 16), 256, 0, stream>>>(x_h, x_l, wqT_h, 6144, 2048, qk_h,
                                                        vt_h, nullptr);
  // dual flash attention + combine + RMS
  diff_attn_kernel<<<dim3(32, 16), 256, 0, stream>>>(qk_h, vt_h, lam, rms, at_h, at_l);
  // out = attn @ w_proj (M=N=K=2048), BM=64 -> 512 blocks (2/CU)
  gemm_bf16x2<1, 64><<<dim3(16, 32), 256, 0, stream>>>(at_h, at_l, wpT_h, 2048, 2048, nullptr,
                                                       nullptr, out);
}

// Round 9
// 354.736 us; speedup vs baseline: 1.8711x; 1.1037x over previous
//
#include <hip/hip_runtime.h>

// DiffSelfAttention on MI355X (gfx950).
// ROUND 9 (= round-8 resubmit; round-8 was a broker timeout, never measured).
// Amortize per-tile stalls. Attn KB=128 (2-half P/PV pass, LDS=80KB, 2 blk/CU),
// GEMMs BK=64 (half the barrier drains, per-kc fragment loads), sw7 swizzle everywhere
// (2-way LDS conflicts), setprio around attn MFMA (T5). Loop skeleton stays the proven
// 2-barrier single-buffer (round-5 issue-early dbuf regressed 2.2x — do not reintroduce).

typedef unsigned short u16;
typedef __attribute__((ext_vector_type(8))) short bf16x8;
typedef __attribute__((ext_vector_type(4))) float f32x4;

#define MFMA16(a, b, c) __builtin_amdgcn_mfma_f32_16x16x32_bf16((a), (b), (c), 0, 0, 0)

#define LAMBDA_INIT_F 0.35550906759096926f
#define ONE_MINUS_LI_F 0.64449093240903074f
#define QSCALE 0.18033688011112042f   // 0.125 * log2(e): scores land in log2 domain
#define DEFER_THR 11.541560327111707f // 8 * log2(e)

__device__ __forceinline__ u16 f2bf(float f) {  // RNE (epilogues)
  union { float f; unsigned u; } v; v.f = f;
  unsigned r = v.u + 0x7fffu + ((v.u >> 16) & 1u);
  return (u16)(r >> 16);
}
__device__ __forceinline__ u16 fastbf(float f) {  // round-up-ties (P values, >=0)
  union { float f; unsigned u; } v; v.f = f;
  return (u16)((v.u + 0x8000u) >> 16);
}
__device__ __forceinline__ float bf2f(u16 h) {
  union { unsigned u; float f; } v; v.u = ((unsigned)h) << 16;
  return v.f;
}
__device__ __forceinline__ int sw7(int row) { return (row & 7) << 3; }
__device__ __forceinline__ float fexp2(float x) { return __builtin_exp2f(x); }

__device__ __forceinline__ void gload16(const u16* g, u16* l) {
  __builtin_amdgcn_global_load_lds((const __attribute__((address_space(1))) void*)g,
                                   (__attribute__((address_space(3))) void*)l,
                                   16, 0, 0);
}

// ---------------- preprocessing ----------------

__global__ void lam_kernel(const float* __restrict__ q1, const float* __restrict__ k1,
                           const float* __restrict__ q2, const float* __restrict__ k2,
                           float* __restrict__ out) {
  int l = threadIdx.x;  // 64
  float p1 = q1[l] * k1[l];
  float p2 = q2[l] * k2[l];
#pragma unroll
  for (int m = 32; m >= 1; m >>= 1) {
    p1 += __shfl_xor(p1, m, 64);
    p2 += __shfl_xor(p2, m, 64);
  }
  if (l == 0) out[0] = expf(p1) - expf(p2) + LAMBDA_INIT_F;
}

// x [2048][2048] f32 -> hi/lo bf16, column-swizzled by sw7(row)
__global__ void split_x_kernel(const float* __restrict__ X, u16* __restrict__ H,
                               u16* __restrict__ L) {
  int idx = blockIdx.x * 256 + threadIdx.x;
  int t = idx >> 9;
  int c0 = (idx & 511) << 2;
  float4 v = *reinterpret_cast<const float4*>(X + ((size_t)t << 11) + c0);
  float vv[4] = {v.x, v.y, v.z, v.w};
  int s = sw7(t);
  size_t base = (size_t)t << 11;
#pragma unroll
  for (int j = 0; j < 4; ++j) {
    int c = (c0 + j) ^ s;
    u16 h = f2bf(vv[j]);
    H[base + c] = h;
    L[base + c] = f2bf(vv[j] - bf2f(h));
  }
}

// W [K][N] f32 -> W^T [N][K] bf16 (hi only), column(k)-swizzled by sw7(n)
__global__ void transpose_kernel(const float* __restrict__ W, u16* __restrict__ TH, int K,
                                 int N) {
  __shared__ float tile[64][65];
  int bk = blockIdx.x * 64, bn = blockIdx.y * 64;
  for (int i = threadIdx.x; i < 64 * 64; i += 256) {
    int r = i >> 6, c = i & 63;
    tile[r][c] = W[(size_t)(bk + r) * N + bn + c];
  }
  __syncthreads();
  for (int i = threadIdx.x; i < 64 * 64; i += 256) {
    int r = i >> 6, c = i & 63;
    float v = tile[c][r];
    int n = bn + r, k = bk + c;
    TH[(size_t)n * K + (k ^ sw7(n))] = f2bf(v);
  }
}

// ---------------- bf16x2 GEMM: C = (Ah+Al) @ Bh^T, BK=64, 2-barrier single-buffer --------
// EPI 0: -> qk_h (q scaled by QSCALE, k sw7) + vt_h (V^T, sw7 on t).  EPI 1: fp32 -> outp
template <int EPI, int BM>
__global__ __launch_bounds__(256, 2) void gemm_bf16x2(
    const u16* __restrict__ Agh, const u16* __restrict__ Agl, const u16* __restrict__ Bgh,
    int N, int K, u16* __restrict__ qk_h, u16* __restrict__ vt_h, float* __restrict__ outp) {
  constexpr int ACH = BM / 8;        // 1KB chunks per A array (BM*64/512)
  constexpr int NCH = 2 * ACH + 16;  // + B chunks (128*64/512)
  constexpr int CPW = NCH / 4;       // chunks per wave
  constexpr int ASZ = BM * 64;       // elems per A array
  constexpr int MR = BM / 32;        // m-fragments per wave
  __shared__ __align__(16) u16 LA[(2 * BM + 128) * 64];  // Ah, Al, Bh (BK=64)
  const int tid = threadIdx.x;
  const int w = tid >> 6, lane = tid & 63;
  const int lr = lane & 15, kg = lane >> 4;
  const int bn0 = blockIdx.x * 128, bm0 = blockIdx.y * BM;
  const int wm = (w >> 1) * (BM / 2), wn = (w & 1) * 64;
  const int srow = lane >> 3, scol = (lane & 7) << 3;  // 8 rows x 128B per 1KB chunk

  f32x4 acc[MR][4];
  const f32x4 VZ = {0.f, 0.f, 0.f, 0.f};
#pragma unroll
  for (int m = 0; m < MR; ++m)
#pragma unroll
    for (int n = 0; n < 4; ++n) acc[m][n] = VZ;

  for (int k0 = 0; k0 < K; k0 += 64) {
    __syncthreads();  // previous tile's reads complete
#pragma unroll
    for (int j = 0; j < CPW; ++j) {
      int i = w * CPW + j;
      int a = (i < ACH) ? 0 : (i < 2 * ACH) ? 1 : 2;
      int c = i - ((a == 0) ? 0 : (a == 1) ? ACH : 2 * ACH);
      const u16* src = (a == 0) ? Agh : (a == 1) ? Agl : Bgh;
      int tb = (a < 2) ? bm0 : bn0;
      gload16(src + (size_t)(tb + c * 8 + srow) * K + k0 + scol, &LA[a * ASZ + c * 512]);
    }
    __syncthreads();  // staging drained (vmcnt(0) before barrier)

#pragma unroll
    for (int kc = 0; kc < 2; ++kc) {  // per-kc fragment loads keep VGPR ~130
      bf16x8 ah[MR], al[MR], bh[4];
#pragma unroll
      for (int m = 0; m < MR; ++m) {
        int row = wm + m * 16 + lr;
        int off = (row << 6) + (((kc << 5) | (kg << 3)) ^ sw7(row));
        ah[m] = *reinterpret_cast<const bf16x8*>(&LA[0] + off);
        al[m] = *reinterpret_cast<const bf16x8*>(&LA[ASZ] + off);
      }
#pragma unroll
      for (int n = 0; n < 4; ++n) {
        int row = wn + n * 16 + lr;
        int off = (row << 6) + (((kc << 5) | (kg << 3)) ^ sw7(row));
        bh[n] = *reinterpret_cast<const bf16x8*>(&LA[2 * ASZ] + off);
      }
#pragma unroll
      for (int m = 0; m < MR; ++m)
#pragma unroll
        for (int n = 0; n < 4; ++n) {
          acc[m][n] = MFMA16(ah[m], bh[n], acc[m][n]);
          acc[m][n] = MFMA16(al[m], bh[n], acc[m][n]);
        }
    }
  }

#pragma unroll
  for (int m = 0; m < MR; ++m) {
#pragma unroll
    for (int n = 0; n < 4; ++n) {
#pragma unroll
      for (int r = 0; r < 4; ++r) {
        int row = bm0 + wm + m * 16 + (kg << 2) + r;  // C/D: row=(lane>>4)*4+reg
        int col = bn0 + wn + n * 16 + lr;             //      col=lane&15
        float v = acc[m][n][r];
        if (EPI == 0) {
          if (col < 2048) v *= QSCALE;  // bake softmax scale * log2e into Q
          u16 hh = f2bf(v);
          if (col < 4096) {  // q plain; k sw7-swizzled within 64-col head slice
            int cc = (col < 2048) ? col : (2048 + ((col - 2048) ^ sw7(row)));
            qk_h[((size_t)row << 12) + cc] = hh;
          } else {  // v -> transposed [vc][t], t sw7-swizzled by vc
            int vc = col - 4096;
            vt_h[((size_t)vc << 11) + (row ^ sw7(vc))] = hh;
          }
        } else {
          outp[(size_t)row * N + col] = v;
        }
      }
    }
  }
}

// ---------------- fused dual flash-attention + lambda-combine + RMS norm ----------------
// grid (T/64, 16 heads), 4 waves; wave owns 16 q-rows; KB=128; 2-barrier single-buffer.
// P/PV in two 64-key half-passes so PL stays 16KB (wave-private reuse). LDS = 80KB.
__global__ __launch_bounds__(256, 2) void diff_attn_kernel(
    const u16* __restrict__ qk_h, const u16* __restrict__ vt_h, const float* __restrict__ lam_p,
    const float* __restrict__ rms_scale, u16* __restrict__ at_h, u16* __restrict__ at_l) {
  __shared__ __align__(16) u16 KL[2][128][64];    // K1, K2 (32 KB), sw7 on d-chunks
  __shared__ __align__(16) u16 VL[128][128];      // V^T (32 KB), sw7 on t-chunks
  __shared__ __align__(16) u16 PL[4][2][16][64];  // per-wave P (16 KB), rotation-swizzled

  const int tid = threadIdx.x;
  const int w = tid >> 6, lane = tid & 63;
  const int lr = lane & 15, kg = lane >> 4;
  const int h = blockIdx.y;
  const int qb = blockIdx.x * 64 + w * 16;
  const float lam = lam_p[0];
  const f32x4 VZ = {0.f, 0.f, 0.f, 0.f};
  const bf16x8 ONES = {0x3f80, 0x3f80, 0x3f80, 0x3f80, 0x3f80, 0x3f80, 0x3f80, 0x3f80};

  // Q fragments (pre-scaled by QSCALE in GEMM1 epilogue): [stream][kchunk]
  bf16x8 qf[2][2];
  {
    const size_t qrb = ((size_t)(qb + lr)) << 12;
#pragma unroll
    for (int s = 0; s < 2; ++s) {
      int qo = h * 64 + s * 1024;
#pragma unroll
      for (int kc = 0; kc < 2; ++kc)
        qf[s][kc] = *reinterpret_cast<const bf16x8*>(qk_h + qrb + qo + kc * 32 + (kg << 3));
    }
  }

  f32x4 o1[8], o2[8];
#pragma unroll
  for (int n = 0; n < 8; ++n) { o1[n] = VZ; o2[n] = VZ; }
  float m[4], l1[4], l2[4];
#pragma unroll
  for (int r = 0; r < 4; ++r) { m[r] = -1e30f; l1[r] = l2[r] = 0.f; }

  const int srow8 = lane >> 3, scol8 = (lane & 7) << 3;    // K chunks: 8 rows x 64
  const int srow4 = lane >> 4, scol4 = (lane & 15) << 3;   // V chunks: 4 rows x 128
  const int koff = 2048 + h * 64 + w * 1024;               // valid for w<2

  for (int kt = 0; kt < 2048; kt += 128) {
    __syncthreads();  // previous tile's LDS reads complete
    if (w < 2) {      // wave0->K1, wave1->K2 (16 x 1KB chunks each)
#pragma unroll
      for (int c = 0; c < 16; ++c)
        gload16(qk_h + (((size_t)(kt + c * 8 + srow8)) << 12) + koff + scol8,
                &KL[w][c * 8][0]);
    } else {          // waves 2,3 -> V d-halves (16 x 1KB chunks each)
      const int vb = (w - 2) * 64;
#pragma unroll
      for (int c = 0; c < 16; ++c)
        gload16(vt_h + (((size_t)(h * 128 + vb + c * 4 + srow4)) << 11) + kt + scol4,
                &VL[vb + c * 4][0]);
    }
    __syncthreads();  // staging drained

    // S = Q K^T over 128 keys (log2 domain; both streams)
    f32x4 s1[8], s2[8];
#pragma unroll
    for (int n = 0; n < 8; ++n) { s1[n] = VZ; s2[n] = VZ; }
    __builtin_amdgcn_s_setprio(1);
#pragma unroll
    for (int n = 0; n < 8; ++n) {
      int key = n * 16 + lr;
#pragma unroll
      for (int kc = 0; kc < 2; ++kc) {
        int off = (key << 6) + (((kc << 5) | (kg << 3)) ^ sw7(key));
        bf16x8 k1 = *reinterpret_cast<const bf16x8*>(&KL[0][0][0] + off);
        bf16x8 k2 = *reinterpret_cast<const bf16x8*>(&KL[1][0][0] + off);
        s1[n] = MFMA16(qf[0][kc], k1, s1[n]);
        s2[n] = MFMA16(qf[1][kc], k2, s2[n]);
      }
    }
    __builtin_amdgcn_s_setprio(0);

    // joint-max over 128 keys (both streams), defer-max
    float tmax[4];
#pragma unroll
    for (int r = 0; r < 4; ++r) {
      float t = fmaxf(fmaxf(fmaxf(s1[0][r], s1[1][r]), fmaxf(s1[2][r], s1[3][r])),
                      fmaxf(fmaxf(s1[4][r], s1[5][r]), fmaxf(s1[6][r], s1[7][r])));
      float t2 = fmaxf(fmaxf(fmaxf(s2[0][r], s2[1][r]), fmaxf(s2[2][r], s2[3][r])),
                       fmaxf(fmaxf(s2[4][r], s2[5][r]), fmaxf(s2[6][r], s2[7][r])));
      t = fmaxf(t, t2);
      t = fmaxf(t, __shfl_xor(t, 1, 64));
      t = fmaxf(t, __shfl_xor(t, 2, 64));
      t = fmaxf(t, __shfl_xor(t, 4, 64));
      t = fmaxf(t, __shfl_xor(t, 8, 64));
      tmax[r] = t;
    }
    int need = 0;
#pragma unroll
    for (int r = 0; r < 4; ++r) need |= (tmax[r] > m[r] + DEFER_THR) ? 1 : 0;
    if (__any(need)) {
#pragma unroll
      for (int r = 0; r < 4; ++r) {
        float mn = fmaxf(m[r], tmax[r]);
        float corr = fexp2(m[r] - mn);
        m[r] = mn;
        l1[r] *= corr;
        l2[r] *= corr;
#pragma unroll
        for (int n = 0; n < 8; ++n) { o1[n][r] *= corr; o2[n][r] *= corr; }
      }
    }

    // two 64-key half-passes: P = exp2(s-m) -> PL (rotation-swizzled, wave-private reuse)
    // -> readback as A-frags -> ones-MFMA row sums -> PV accumulate
#pragma unroll
    for (int hs = 0; hs < 2; ++hs) {
#pragma unroll
      for (int nn = 0; nn < 4; ++nn) {
        int n = hs * 4 + nn;
#pragma unroll
        for (int r = 0; r < 4; ++r) {
          float p1 = fexp2(s1[n][r] - m[r]);
          float p2 = fexp2(s2[n][r] - m[r]);
          int qp = (nn * 2 + (lr >> 3) + kg + 2 * r) & 7;
          int idx = qp * 8 + (lr & 7);
          PL[w][0][4 * kg + r][idx] = fastbf(p1);
          PL[w][1][4 * kg + r][idx] = fastbf(p2);
        }
      }
      bf16x8 pa1[2], pa2[2];
#pragma unroll
      for (int ks = 0; ks < 2; ++ks) {
        int qp = (ks * 4 + kg + (lr >> 2) + 2 * (lr & 3)) & 7;
        pa1[ks] = *reinterpret_cast<const bf16x8*>(&PL[w][0][lr][qp * 8]);
        pa2[ks] = *reinterpret_cast<const bf16x8*>(&PL[w][1][lr][qp * 8]);
      }
      f32x4 lacc1 = MFMA16(pa1[1], ONES, MFMA16(pa1[0], ONES, VZ));
      f32x4 lacc2 = MFMA16(pa2[1], ONES, MFMA16(pa2[0], ONES, VZ));
#pragma unroll
      for (int r = 0; r < 4; ++r) { l1[r] += lacc1[r]; l2[r] += lacc2[r]; }

      __builtin_amdgcn_s_setprio(1);
#pragma unroll
      for (int n = 0; n < 8; ++n) {
        int vd = n * 16 + lr;
#pragma unroll
        for (int ks = 0; ks < 2; ++ks) {
          int off = (vd << 7) + ((((hs * 2 + ks) << 5) | (kg << 3)) ^ sw7(vd));
          bf16x8 vf = *reinterpret_cast<const bf16x8*>(&VL[0][0] + off);
          o1[n] = MFMA16(pa1[ks], vf, o1[n]);
          o2[n] = MFMA16(pa2[ks], vf, o2[n]);
        }
      }
      __builtin_amdgcn_s_setprio(0);
    }
  }

  // epilogue: a1 - lam*a2, RMS over 128, * rms_scale * (1-LAMBDA_INIT); hi/lo split for GEMM2
  float nsc[4];
  {
    float il1[4], il2[4], ss[4];
#pragma unroll
    for (int r = 0; r < 4; ++r) { il1[r] = 1.f / l1[r]; il2[r] = 1.f / l2[r]; ss[r] = 0.f; }
#pragma unroll
    for (int n = 0; n < 8; ++n)
#pragma unroll
      for (int r = 0; r < 4; ++r) {
        float v = o1[n][r] * il1[r] - lam * (o2[n][r] * il2[r]);
        o1[n][r] = v;
        ss[r] += v * v;
      }
#pragma unroll
    for (int r = 0; r < 4; ++r) {
      float t = ss[r];
      t += __shfl_xor(t, 1, 64);
      t += __shfl_xor(t, 2, 64);
      t += __shfl_xor(t, 4, 64);
      t += __shfl_xor(t, 8, 64);
      nsc[r] = rsqrtf(t * (1.f / 128.f) + 1e-6f) * ONE_MINUS_LI_F;
    }
  }
#pragma unroll
  for (int n = 0; n < 8; ++n) {
    float rs = rms_scale[n * 16 + lr];
#pragma unroll
    for (int r = 0; r < 4; ++r) {
      int row = qb + (kg << 2) + r;
      int col = h * 128 + n * 16 + lr;
      float v = o1[n][r] * nsc[r] * rs;
      u16 hh = f2bf(v);
      int cc = col ^ sw7(row);
      at_h[((size_t)row << 11) + cc] = hh;
      at_l[((size_t)row << 11) + cc] = f2bf(v - bf2f(hh));
    }
  }
}

// ---------------- launch ----------------

extern "C" void kernel_launch(void* const* d_in, const int* in_sizes, int n_in, void* d_out,
                              int out_size, void* d_ws, size_t ws_size, hipStream_t stream) {
  (void)in_sizes; (void)n_in; (void)out_size;
  const float* x = (const float*)d_in[0];
  const float* wqkv = (const float*)d_in[1];
  const float* wprj = (const float*)d_in[2];
  const float* lq1 = (const float*)d_in[3];
  const float* lk1 = (const float*)d_in[4];
  const float* lq2 = (const float*)d_in[5];
  const float* lk2 = (const float*)d_in[6];
  const float* rms = (const float*)d_in[7];
  float* out = (float*)d_out;

  char* p = (char*)d_ws;
  auto take = [&](size_t n) { char* r = p; p += (n + 255) & ~(size_t)255; return r; };
  float* lam = (float*)take(256);
  u16* x_h = (u16*)take(2048ull * 2048 * 2);
  u16* x_l = (u16*)take(2048ull * 2048 * 2);
  u16* wqT_h = (u16*)take(6144ull * 2048 * 2);
  u16* wpT_h = (u16*)take(2048ull * 2048 * 2);
  u16* qk_h = (u16*)take(2048ull * 4096 * 2);
  u16* vt_h = (u16*)take(2048ull * 2048 * 2);
  u16* at_h = (u16*)take(2048ull * 2048 * 2);
  u16* at_l = (u16*)take(2048ull * 2048 * 2);
  if ((size_t)(p - (char*)d_ws) > ws_size) return;

  lam_kernel<<<1, 64, 0, stream>>>(lq1, lk1, lq2, lk2, lam);
  split_x_kernel<<<4096, 256, 0, stream>>>(x, x_h, x_l);
  transpose_kernel<<<dim3(32, 96), 256, 0, stream>>>(wqkv, wqT_h, 2048, 6144);
  transpose_kernel<<<dim3(32, 32), 256, 0, stream>>>(wprj, wpT_h, 2048, 2048);

  // qkv = x @ w_qkv (M=2048, N=6144, K=2048) -> qk_h (q pre-scaled) + vt_h
  gemm_bf16x2<0, 128><<<dim3(48, 16), 256, 0, stream>>>(x_h, x_l, wqT_h, 6144, 2048, qk_h,
                                                        vt_h, nullptr);
  // dual flash attention + combine + RMS (KB=128)
  diff_attn_kernel<<<dim3(32, 16), 256, 0, stream>>>(qk_h, vt_h, lam, rms, at_h, at_l);
  // out = attn @ w_proj (M=N=K=2048), BM=64 -> 512 blocks (2/CU)
  gemm_bf16x2<1, 64><<<dim3(16, 32), 256, 0, stream>>>(at_h, at_l, wpT_h, 2048, 2048, nullptr,
                                                       nullptr, out);
}